// Round 2
// baseline (181.245 us; speedup 1.0000x reference)
//
#include <hip/hip_runtime.h>
#include <stdint.h>

#define Bn 16
#define Sn 2048
#define Dn 128
#define QBLK 64
#define KVBLK 64

typedef __attribute__((ext_vector_type(4))) float f32x4;
typedef __attribute__((ext_vector_type(8))) short bf16x8;   // 8 bf16 = 4 VGPRs
typedef __attribute__((ext_vector_type(2))) unsigned int u32x2;

// LDS layout (bytes):
//  K  : [64][128] bf16 row-major, swizzled  byte(k,d) = (k*256 + d*2) ^ ((k&7)<<4)      16384 B
//  VT : [128][72] bf16 (V transposed, row stride 144 B): byte(d,k) = d*144 + k*2        18432 B
//       (pad 144 = 36 dwords -> rows hit distinct bank groups; no swizzle needed)
//  P  : per-wave [16][64] bf16, swizzled    byte(q,k) = (q*128 + k*2) ^ ((q&7)<<4)    4*2048 B
#define KOFF 0
#define VTOFF 16384
#define POFF 34816
#define SMEM_BYTES 43008

__device__ __forceinline__ uint32_t f2bf_u(float f) {   // fp32 -> bf16 bits, RNE
  uint32_t x = __float_as_uint(f);
  return (x + 0x7fffu + ((x >> 16) & 1u)) >> 16;
}

__global__ __launch_bounds__(256, 2) void attn_fwd(
    const float* __restrict__ Q, const float* __restrict__ K,
    const float* __restrict__ V, float* __restrict__ O) {
  __shared__ uint4 smem_[SMEM_BYTES / 16];
  char* smem = (char*)smem_;

  const int tid = threadIdx.x;
  const int lane = tid & 63;
  const int w = tid >> 6;        // wave id 0..3
  const int g = lane >> 4;       // 16-lane group 0..3
  const int c = lane & 15;
  const int b = blockIdx.y;
  const int q0 = blockIdx.x * QBLK;

  // ---- Q fragments: A-operand layout, row = lane%16, k = (lane/16)*8 + j (+32*kk) ----
  // fold 1/sqrt(128) * log2(e) into Q so softmax uses exp2 directly
  const float qscale = 0.08838834764831845f * 1.44269504088896340736f;
  bf16x8 qf[4];
  {
    const float* qrow = Q + ((size_t)(b * Sn + q0 + w * 16 + c)) * Dn;
#pragma unroll
    for (int kk = 0; kk < 4; ++kk) {
      const float4 a = *(const float4*)(qrow + g * 8 + kk * 32);
      const float4 d = *(const float4*)(qrow + g * 8 + kk * 32 + 4);
      bf16x8 q8;
      q8[0] = (short)f2bf_u(a.x * qscale); q8[1] = (short)f2bf_u(a.y * qscale);
      q8[2] = (short)f2bf_u(a.z * qscale); q8[3] = (short)f2bf_u(a.w * qscale);
      q8[4] = (short)f2bf_u(d.x * qscale); q8[5] = (short)f2bf_u(d.y * qscale);
      q8[6] = (short)f2bf_u(d.z * qscale); q8[7] = (short)f2bf_u(d.w * qscale);
      qf[kk] = q8;
    }
  }

  f32x4 acc[8];
#pragma unroll
  for (int i = 0; i < 8; ++i) acc[i] = (f32x4){0.f, 0.f, 0.f, 0.f};
  float m_r[4], l_r[4];
#pragma unroll
  for (int r = 0; r < 4; ++r) { m_r[r] = -3.0e38f; l_r[r] = 0.f; }

  const float4* Kg4 = (const float4*)(K + (size_t)b * Sn * Dn);
  const float* Vg_base = V + (size_t)b * Sn * Dn;
  const uint32_t pbase = POFF + w * 2048;

  for (int kv = 0; kv < Sn; kv += KVBLK) {
    __syncthreads();   // all waves done reading previous K/VT tiles

    // ---- stage K tile: fp32 global (float4, coalesced) -> bf16 swizzled LDS ----
    {
      const int kvrow4 = kv * (Dn / 4);
#pragma unroll
      for (int it = 0; it < 8; ++it) {
        const int gr = it * 256 + tid;
        const int k = gr >> 5;          // row in tile 0..63
        const int dg = gr & 31;         // float4 granule in row
        float4 kvv = Kg4[kvrow4 + k * 32 + dg];
        u32x2 wv;
        wv.x = f2bf_u(kvv.x) | (f2bf_u(kvv.y) << 16);
        wv.y = f2bf_u(kvv.z) | (f2bf_u(kvv.w) << 16);
        uint32_t koffb = (uint32_t)(k * 256 + dg * 8) ^ (uint32_t)((k & 7) << 4);
        *(u32x2*)(smem + KOFF + koffb) = wv;
      }
    }

    // ---- stage V tile TRANSPOSED: VT[d][k], d = tid&127 ----
    // load i: lanes read 64 consecutive floats (coalesced); store: one 16B row-chunk
    {
      const float* Vg = Vg_base + (size_t)kv * Dn;
      const int d = tid & 127;
      const int kb2 = tid >> 7;   // 0 or 1
#pragma unroll
      for (int it = 0; it < 4; ++it) {
        const int k0 = kb2 * 8 + it * 16;
        uint32_t pk0, pk1, pk2, pk3;
        {
          float v0 = Vg[(k0 + 0) * Dn + d], v1 = Vg[(k0 + 1) * Dn + d];
          float v2 = Vg[(k0 + 2) * Dn + d], v3 = Vg[(k0 + 3) * Dn + d];
          float v4 = Vg[(k0 + 4) * Dn + d], v5 = Vg[(k0 + 5) * Dn + d];
          float v6 = Vg[(k0 + 6) * Dn + d], v7 = Vg[(k0 + 7) * Dn + d];
          pk0 = f2bf_u(v0) | (f2bf_u(v1) << 16);
          pk1 = f2bf_u(v2) | (f2bf_u(v3) << 16);
          pk2 = f2bf_u(v4) | (f2bf_u(v5) << 16);
          pk3 = f2bf_u(v6) | (f2bf_u(v7) << 16);
        }
        *(uint4*)(smem + VTOFF + d * 144 + k0 * 2) = make_uint4(pk0, pk1, pk2, pk3);
      }
    }
    __syncthreads();

    // ---- QK^T: S[16 q][64 k], 4 col-frags x 4 k-steps ----
    f32x4 sv[4];
#pragma unroll
    for (int kf = 0; kf < 4; ++kf) {
      f32x4 s = (f32x4){0.f, 0.f, 0.f, 0.f};
      const int row = kf * 16 + c;   // key index = B-operand col (lane%16)
#pragma unroll
      for (int kk = 0; kk < 4; ++kk) {
        uint32_t off = (uint32_t)(row * 256 + g * 16 + kk * 64) ^
                       (uint32_t)((row & 7) << 4);
        bf16x8 kb = *(const bf16x8*)(smem + KOFF + off);
        s = __builtin_amdgcn_mfma_f32_16x16x32_bf16(qf[kk], kb, s, 0, 0, 0);
      }
      sv[kf] = s;
    }

    // ---- online softmax (C-layout: lane owns rows 4g+r, col c, per col-frag) ----
    float rmax[4];
#pragma unroll
    for (int r = 0; r < 4; ++r)
      rmax[r] = fmaxf(fmaxf(sv[0][r], sv[1][r]), fmaxf(sv[2][r], sv[3][r]));
#pragma unroll
    for (int r = 0; r < 4; ++r) {
#pragma unroll
      for (int msk = 1; msk < 16; msk <<= 1)
        rmax[r] = fmaxf(rmax[r], __shfl_xor(rmax[r], msk, 64));
    }
    float alpha[4], mnew[4];
#pragma unroll
    for (int r = 0; r < 4; ++r) {
      mnew[r] = fmaxf(m_r[r], rmax[r]);
      alpha[r] = __builtin_amdgcn_exp2f(m_r[r] - mnew[r]);
      m_r[r] = mnew[r];
    }
    float rsum[4] = {0.f, 0.f, 0.f, 0.f};
#pragma unroll
    for (int kf = 0; kf < 4; ++kf) {
#pragma unroll
      for (int r = 0; r < 4; ++r) {
        float p = __builtin_amdgcn_exp2f(sv[kf][r] - mnew[r]);
        rsum[r] += p;
        const int prow = g * 4 + r;
        uint32_t poffb = (uint32_t)(prow * 128 + (kf * 16 + c) * 2) ^
                         (uint32_t)((prow & 7) << 4);
        *(unsigned short*)(smem + pbase + poffb) = (unsigned short)f2bf_u(p);
      }
    }
#pragma unroll
    for (int r = 0; r < 4; ++r) {
#pragma unroll
      for (int msk = 1; msk < 16; msk <<= 1)
        rsum[r] += __shfl_xor(rsum[r], msk, 64);
      l_r[r] = l_r[r] * alpha[r] + rsum[r];
    }
    f32x4 av;
    av[0] = alpha[0]; av[1] = alpha[1]; av[2] = alpha[2]; av[3] = alpha[3];
#pragma unroll
    for (int i = 0; i < 8; ++i) acc[i] *= av;

    // P store -> P load: same wave; LDS ops per-wave are in-order. Fence compiler.
    asm volatile("" ::: "memory");

    // ---- P fragments (A-operand) from per-wave P_lds ----
    bf16x8 pa[2];
#pragma unroll
    for (int kk2 = 0; kk2 < 2; ++kk2) {
      uint32_t off = (uint32_t)(c * 128 + g * 16 + kk2 * 64) ^
                     (uint32_t)((c & 7) << 4);
      pa[kk2] = *(const bf16x8*)(smem + pbase + off);
    }

    // ---- PV: O[16 q][128 d] += P[16][64] * V[64][128], V read from VT rows ----
#pragma unroll
    for (int df = 0; df < 8; ++df) {
      const int dcol = df * 16 + c;
      bf16x8 v0 = *(const bf16x8*)(smem + VTOFF + dcol * 144 + g * 16);
      bf16x8 v1 = *(const bf16x8*)(smem + VTOFF + dcol * 144 + g * 16 + 64);
      acc[df] = __builtin_amdgcn_mfma_f32_16x16x32_bf16(pa[0], v0, acc[df], 0, 0, 0);
      acc[df] = __builtin_amdgcn_mfma_f32_16x16x32_bf16(pa[1], v1, acc[df], 0, 0, 0);
    }
  }

  // ---- epilogue: normalize and store fp32 ----
  float invl[4];
#pragma unroll
  for (int r = 0; r < 4; ++r) invl[r] = 1.0f / l_r[r];
  float* orow = O + ((size_t)(b * Sn + q0 + w * 16 + g * 4)) * Dn;
#pragma unroll
  for (int r = 0; r < 4; ++r) {
#pragma unroll
    for (int df = 0; df < 8; ++df) {
      orow[r * Dn + df * 16 + c] = acc[df][r] * invl[r];
    }
  }
}

extern "C" void kernel_launch(void* const* d_in, const int* in_sizes, int n_in,
                              void* d_out, int out_size, void* d_ws, size_t ws_size,
                              hipStream_t stream) {
  (void)in_sizes; (void)n_in; (void)d_ws; (void)ws_size; (void)out_size;
  const float* Q = (const float*)d_in[0];
  const float* K = (const float*)d_in[1];
  const float* V = (const float*)d_in[2];
  float* O = (float*)d_out;
  dim3 grid(Sn / QBLK, Bn, 1);
  attn_fwd<<<grid, dim3(256, 1, 1), 0, stream>>>(Q, K, V, O);
}